// Round 9
// baseline (349.357 us; speedup 1.0000x reference)
//
#include <hip/hip_runtime.h>

// DIN attention unit, MI355X — round 9.
// R8 diagnosis: pass1 had NO accumulation loop (1 iter/thread), so the
// compiler sank the dot products into the 384-shuffle butterfly and
// recomputed lazily (VGPR=56 proved s[32]/q[32] never materialized).
// Fixes: (1) pass1 streams 8 positions/thread across 2 iterations ->
// accumulators must live; (2) reduce-scatter epilogue: 63 shuffles, not
// 384 (each stage keeps half the values, exchanges the other half);
// (3) pass2/3 j-loop fully unrolled for whole-kernel s_load lookahead.
// mask input UNUSED (reference uses unmasked scores — reproduced bug).

#define BB 512
#define TT 2048
#define DD 20
#define C0 32
#define C1 16

#define NTH 256
#define NPOS 4             // positions per thread per iteration
#define POSB (NTH * NPOS)  // 1024 positions per j-loop pass

// ws float offsets
#define WS_SUM0 0   // [0..31]  layer1 sum
#define WS_SQ0 32   // [32..63] layer1 sumsq
#define WS_SUM1 64  // [64..79] layer2 sum
#define WS_SQ1 80   // [80..95] layer2 sumsq
#define WS_BLOB 192
#define BLOB_J 24             // 20 wM + c + pad
#define BLOB_B (C0 * BLOB_J)  // 768 floats per batch
#define EPS 1e-9f

#define PIN(x) asm volatile("" : "+v"(x))

__device__ __forceinline__ float fast_sigmoid(float x) {
    return __builtin_amdgcn_rcpf(1.0f + __expf(-x));
}

__device__ __forceinline__ void load_krow(const float* __restrict__ row,
                                          float* kk) {
    const float4* kr = (const float4*)row;  // rows are 80B => 16B aligned
    float4 a = kr[0], b = kr[1], c = kr[2], d = kr[3], e = kr[4];
    kk[0] = a.x; kk[1] = a.y; kk[2] = a.z; kk[3] = a.w;
    kk[4] = b.x; kk[5] = b.y; kk[6] = b.z; kk[7] = b.w;
    kk[8] = c.x; kk[9] = c.y; kk[10] = c.z; kk[11] = c.w;
    kk[12] = d.x; kk[13] = d.y; kk[14] = d.z; kk[15] = d.w;
    kk[16] = e.x; kk[17] = e.y; kk[18] = e.z; kk[19] = e.w;
}

// Reduce-scatter butterfly: vals[64] per lane -> lane l returns the
// wave-total of value l. 63 shfl (vs 384 for keep-all butterfly).
__device__ __forceinline__ float reduce_scatter_64(float* vals, int lane) {
#pragma unroll
    for (int m = 32; m >= 1; m >>= 1) {  // value count = 2m entering stage
        bool hi = (lane & m) != 0;
#pragma unroll
        for (int i = 0; i < m; ++i) {
            float keep = hi ? vals[m + i] : vals[i];
            float send = hi ? vals[i] : vals[m + i];
            vals[i] = keep + __shfl_xor(send, m);
        }
    }
    return vals[0];
}

// 32 values across 64 lanes: pre-fold the lane halves, then 5 stages.
// Lane l (and l^32) returns the wave-total of value (l & 31).
__device__ __forceinline__ float reduce_scatter_32(float* vals, int lane) {
#pragma unroll
    for (int i = 0; i < 32; ++i) vals[i] += __shfl_xor(vals[i], 32);
#pragma unroll
    for (int m = 16; m >= 1; m >>= 1) {
        bool hi = (lane & m) != 0;
#pragma unroll
        for (int i = 0; i < m; ++i) {
            float keep = hi ? vals[m + i] : vals[i];
            float send = hi ? vals[i] : vals[m + i];
            vals[i] = keep + __shfl_xor(send, m);
        }
    }
    return vals[0];
}

// ---------------- prep: fold query into layer-1 weights (global) --------
// att=[q,k,q-k,q*k]@W0+b0 == c_b + k·M_b ; M=W0_k-W0_d+diag(q)W0_p.
__global__ void prep_kernel(const float* __restrict__ query,
                            const float* __restrict__ W0,
                            const float* __restrict__ b0,
                            float* __restrict__ blob) {
    const int b = blockIdx.x * 2 + (threadIdx.x >> 5);
    const int j = threadIdx.x & 31;
    float cj = b0[j];
    float* dst = blob + (size_t)b * BLOB_B + j * BLOB_J;
#pragma unroll
    for (int d = 0; d < DD; ++d) {
        float w_q = W0[d * C0 + j];
        float w_k = W0[(DD + d) * C0 + j];
        float w_d = W0[(2 * DD + d) * C0 + j];
        float w_p = W0[(3 * DD + d) * C0 + j];
        float qd = query[b * DD + d];
        dst[d] = w_k - w_d + qd * w_p;
        cj = fmaf(qd, w_q + w_d, cj);
    }
    dst[20] = cj;
}

// ---------------- pass 1: layer-1 pre-activation stats ----------------
// One block per batch; thread streams 8 positions (2 iters x 4). s[32]/q[32]
// accumulate ACROSS iterations -> cannot be sunk. Weights via s_load.
__global__ __launch_bounds__(NTH, 2) void pass1_kernel(
    const float* __restrict__ keys, const float* __restrict__ blob,
    float* __restrict__ ws) {
    const int b = blockIdx.x;
    const int tid = threadIdx.x, wave = tid >> 6, lane = tid & 63;
    const float* kbase = keys + (size_t)b * TT * DD;
    const float* wb = blob + (size_t)b * BLOB_B;

    float s[C0], q[C0];
#pragma unroll
    for (int j = 0; j < C0; ++j) { s[j] = 0.f; q[j] = 0.f; }

#pragma unroll 1
    for (int it = 0; it < TT / POSB; ++it) {
        float kk[NPOS][DD];
#pragma unroll
        for (int pp = 0; pp < NPOS; ++pp)
            load_krow(kbase + (size_t)(it * POSB + pp * NTH + tid) * DD,
                      kk[pp]);
#pragma unroll
        for (int pp = 0; pp < NPOS; ++pp)
#pragma unroll
            for (int d = 0; d < DD; ++d) PIN(kk[pp][d]);

#pragma unroll
        for (int j = 0; j < C0; ++j) {
            const float* w = wb + j * BLOB_J;  // uniform -> s_load
            float h[NPOS];
#pragma unroll
            for (int pp = 0; pp < NPOS; ++pp) {
                float hh = w[20];
#pragma unroll
                for (int d = 0; d < DD; ++d) hh = fmaf(kk[pp][d], w[d], hh);
                h[pp] = hh;
            }
            s[j] += (h[0] + h[1]) + (h[2] + h[3]);
#pragma unroll
            for (int pp = 0; pp < NPOS; ++pp) q[j] = fmaf(h[pp], h[pp], q[j]);
        }
    }

    float vals[64];
#pragma unroll
    for (int v = 0; v < 64; ++v) vals[v] = (v < C0) ? s[v] : q[v - C0];
    float tot = reduce_scatter_64(vals, lane);
    __shared__ float red[4][64];
    red[wave][lane] = tot;
    __syncthreads();
    if (tid < 64)
        atomicAdd(&ws[tid],
                  red[0][tid] + red[1][tid] + red[2][tid] + red[3][tid]);
}

// Load NPOS key rows and PIN them (defeat rematerialization).
#define LOAD_AND_PIN_KEYS()                                                  \
    const float* kbase = keys + ((size_t)b * TT + chunk * POSB) * DD;        \
    float kk[NPOS][DD];                                                      \
    _Pragma("unroll") for (int pp = 0; pp < NPOS; ++pp)                      \
        load_krow(kbase + (size_t)(tid + pp * NTH) * DD, kk[pp]);            \
    _Pragma("unroll") for (int pp = 0; pp < NPOS; ++pp)                      \
        _Pragma("unroll") for (int d = 0; d < DD; ++d) PIN(kk[pp][d]);

// j-loop, FULLY unrolled: wM + W1 via s_load, dice params via one broadcast
// ds_read_b128 per j. Produces h1[NPOS][C1] (layer-2 preact minus b1).
#define TOWER_JLOOP()                                                        \
    _Pragma("unroll") for (int j = 0; j < C0; ++j) {                         \
        float4 P = ld0[j]; /* {c, sc0, sh0, al0} broadcast b128 */           \
        const float* w = wb + j * BLOB_J; /* uniform -> s_load */            \
        const float* u = W1 + j * C1;     /* uniform -> s_load */            \
        float h[NPOS];                                                       \
        _Pragma("unroll") for (int pp = 0; pp < NPOS; ++pp) {                \
            float hh = P.x;                                                  \
            _Pragma("unroll") for (int d = 0; d < DD; ++d)                   \
                hh = fmaf(kk[pp][d], w[d], hh);                              \
            h[pp] = hh;                                                      \
        }                                                                    \
        float oml = 1.0f - P.w;                                              \
        _Pragma("unroll") for (int pp = 0; pp < NPOS; ++pp) {                \
            float pr = fast_sigmoid(fmaf(h[pp], P.y, P.z));                  \
            float h0d = h[pp] * fmaf(pr, oml, P.w);                          \
            _Pragma("unroll") for (int c = 0; c < C1; ++c)                   \
                h1[pp][c] = fmaf(h0d, u[c], h1[pp][c]);                      \
        }                                                                    \
    }

// Stage {c, sc0, sh0, al0} per layer-1 channel into LDS (from atomic sums).
#define STAGE_DICE0()                                                        \
    if (tid < C0) {                                                          \
        const float invN = 1.0f / (float)(BB * TT);                          \
        float mean = ws[WS_SUM0 + tid] * invN;                               \
        float ex2 = ws[WS_SQ0 + tid] * invN;                                 \
        float sc = rsqrtf(ex2 - mean * mean + EPS);                          \
        ld0[tid] = make_float4(blob[(size_t)b * BLOB_B + tid * BLOB_J + 20], \
                               sc, -mean * sc, a0[tid]);                     \
    }

// ---------------- pass 2: layer-2 pre-activation stats ----------------
__global__ __launch_bounds__(NTH, 2) void pass2_kernel(
    const float* __restrict__ keys, const float* __restrict__ blob,
    const float* __restrict__ a0, const float* __restrict__ W1,
    const float* __restrict__ b1, float* __restrict__ ws) {
    const int b = blockIdx.x >> 1, chunk = blockIdx.x & 1;
    const int tid = threadIdx.x, wave = tid >> 6, lane = tid & 63;
    const float* wb = blob + (size_t)b * BLOB_B;
    __shared__ float4 ld0[C0];
    __shared__ float red[4][32];
    STAGE_DICE0()
    __syncthreads();

    LOAD_AND_PIN_KEYS()

    float h1[NPOS][C1];
#pragma unroll
    for (int pp = 0; pp < NPOS; ++pp)
#pragma unroll
        for (int c = 0; c < C1; ++c) h1[pp][c] = 0.f;

    TOWER_JLOOP()

    float vals[32];
#pragma unroll
    for (int c = 0; c < C1; ++c) {
        float bc = b1[c], sv = 0.f, qv = 0.f;
#pragma unroll
        for (int pp = 0; pp < NPOS; ++pp) {
            float v = h1[pp][c] + bc;
            sv += v;
            qv = fmaf(v, v, qv);
        }
        vals[c] = sv;
        vals[C1 + c] = qv;
    }
    float tot = reduce_scatter_32(vals, lane);
    if (lane < 32) red[wave][lane] = tot;
    __syncthreads();
    if (tid < 32)
        atomicAdd(&ws[WS_SUM1 + tid],
                  red[0][tid] + red[1][tid] + red[2][tid] + red[3][tid]);
}

// ---------------- pass 3: full tower + weighted key-sum ----------------
__global__ __launch_bounds__(NTH, 2) void pass3_kernel(
    const float* __restrict__ keys, const float* __restrict__ blob,
    const float* __restrict__ a0, const float* __restrict__ W1,
    const float* __restrict__ b1, const float* __restrict__ a1,
    const float* __restrict__ wk, const float* __restrict__ bk,
    const float* __restrict__ ws, float* __restrict__ out) {
    const int b = blockIdx.x >> 1, chunk = blockIdx.x & 1;
    const int tid = threadIdx.x, wave = tid >> 6, lane = tid & 63;
    const float* wb = blob + (size_t)b * BLOB_B;
    __shared__ float4 ld0[C0];
    __shared__ float4 ld1[C1];  // {sc1, sh1, al1, wk}
    __shared__ float red[4][32];
    STAGE_DICE0()
    if (tid < C1) {
        const float invN = 1.0f / (float)(BB * TT);
        float mean = ws[WS_SUM1 + tid] * invN;
        float ex2 = ws[WS_SQ1 + tid] * invN;
        float sc = rsqrtf(ex2 - mean * mean + EPS);
        ld1[tid] = make_float4(sc, -mean * sc, a1[tid], wk[tid]);
    }
    __syncthreads();

    LOAD_AND_PIN_KEYS()

    float h1[NPOS][C1];
#pragma unroll
    for (int pp = 0; pp < NPOS; ++pp)
#pragma unroll
        for (int c = 0; c < C1; ++c) h1[pp][c] = 0.f;

    TOWER_JLOOP()

    const float bkv = bk[0];
    float oacc[DD];
#pragma unroll
    for (int d = 0; d < DD; ++d) oacc[d] = 0.f;
#pragma unroll
    for (int pp = 0; pp < NPOS; ++pp) {
        float score = bkv;
#pragma unroll
        for (int c = 0; c < C1; ++c) {
            float v = h1[pp][c] + b1[c];
            float4 Q = ld1[c];
            float pr = fast_sigmoid(fmaf(v, Q.x, Q.y));
            float hd = v * fmaf(pr, 1.0f - Q.z, Q.z);
            score = fmaf(hd, Q.w, score);
        }
#pragma unroll
        for (int d = 0; d < DD; ++d) oacc[d] = fmaf(score, kk[pp][d], oacc[d]);
    }
    float vals[32];
#pragma unroll
    for (int v = 0; v < 32; ++v) vals[v] = (v < DD) ? oacc[v] : 0.f;
    float tot = reduce_scatter_32(vals, lane);
    if (lane < 32) red[wave][lane] = tot;
    __syncthreads();
    if (tid < DD)
        atomicAdd(&out[b * DD + tid],
                  red[0][tid] + red[1][tid] + red[2][tid] + red[3][tid]);
}

extern "C" void kernel_launch(void* const* d_in, const int* in_sizes, int n_in,
                              void* d_out, int out_size, void* d_ws,
                              size_t ws_size, hipStream_t stream) {
    const float* keys = (const float*)d_in[0];
    const float* query = (const float*)d_in[1];
    // d_in[2] = mask: intentionally unused
    const float* W0 = (const float*)d_in[3];
    const float* b0 = (const float*)d_in[4];
    const float* a0 = (const float*)d_in[5];
    const float* W1 = (const float*)d_in[6];
    const float* b1 = (const float*)d_in[7];
    const float* a1 = (const float*)d_in[8];
    const float* wk = (const float*)d_in[9];
    const float* bk = (const float*)d_in[10];
    float* out = (float*)d_out;
    float* ws = (float*)d_ws;
    float* blob = ws + WS_BLOB;  // 512*768 floats = 1.5 MB scratch

    hipMemsetAsync(ws, 0, 96 * sizeof(float), stream);
    hipMemsetAsync(out, 0, (size_t)out_size * sizeof(float), stream);

    prep_kernel<<<BB / 2, 64, 0, stream>>>(query, W0, b0, blob);

    pass1_kernel<<<BB, NTH, 0, stream>>>(keys, blob, ws);
    pass2_kernel<<<BB * 2, NTH, 0, stream>>>(keys, blob, a0, W1, b1, ws);
    pass3_kernel<<<BB * 2, NTH, 0, stream>>>(keys, blob, a0, W1, b1, a1, wk,
                                             bk, ws, out);
}